// Round 12
// baseline (176.716 us; speedup 1.0000x reference)
//
#include <hip/hip_runtime.h>
#include <cstddef>

#define E_DIM 512
#define HID   640
#define NH    10
#define DK    64
#define LTOT  2054
#define NCLS  527
#define NB    4
#define KC    (-0.0179889460390157f)   // -ln(10000)/512
#define FPITCH 516                     // padded LDS row pitch (floats): 516%32=4 -> bank-spread, 16B-aligned

// Wave64 sum-reduction via DPP (VALU pipe only).
__device__ __forceinline__ float wave_reduce_sum_dpp(float x) {
    float t;
    t = __int_as_float(__builtin_amdgcn_update_dpp(0, __float_as_int(x), 0x111, 0xf, 0xf, false)); x += t;
    t = __int_as_float(__builtin_amdgcn_update_dpp(0, __float_as_int(x), 0x112, 0xf, 0xf, false)); x += t;
    t = __int_as_float(__builtin_amdgcn_update_dpp(0, __float_as_int(x), 0x114, 0xf, 0xe, false)); x += t;
    t = __int_as_float(__builtin_amdgcn_update_dpp(0, __float_as_int(x), 0x118, 0xf, 0xc, false)); x += t;
    t = __int_as_float(__builtin_amdgcn_update_dpp(0, __float_as_int(x), 0x142, 0xa, 0xf, false)); x += t;
    t = __int_as_float(__builtin_amdgcn_update_dpp(0, __float_as_int(x), 0x143, 0xc, 0xf, false)); x += t;
    return __int_as_float(__builtin_amdgcn_readlane(__float_as_int(x), 63));
}

__device__ __forceinline__ void fma4(float4& a, const float4& x, const float4& y) {
    a.x = fmaf(x.x, y.x, a.x); a.y = fmaf(x.y, y.y, a.y);
    a.z = fmaf(x.z, y.z, a.z); a.w = fmaf(x.w, y.w, a.w);
}

// Source row pointer for logical feats row n of batch b.
__device__ __forceinline__ const float* row_src(int b, int n,
        const float* au, const float* vi, const float* at,
        const float* vt, const float* bt) {
    if (n < 1024) return au + ((size_t)b*1024 + n)*E_DIM;
    if (n == 1024) return at;
    if (n < 1029) return bt + (size_t)(n-1025)*E_DIM;
    if (n < 2053) return vi + ((size_t)b*1024 + (n-1029))*E_DIM;
    return vt;
}

// K1: per-(h,bm) k-fragment + u-vector + c. grid (NH, 8), block 256.
__global__ __launch_bounds__(256) void ba_ku_kernel(
        const float* __restrict__ audio, const float* __restrict__ video,
        const float* __restrict__ Wk, const float* __restrict__ bk,
        const float* __restrict__ Wq, const float* __restrict__ bq,
        float* __restrict__ uws, float* __restrict__ cws) {
    int h = blockIdx.x, bm = blockIdx.y;
    int b = bm >> 1, m = bm & 1;
    int mrow = m ? 1029 : 0;
    const float* src = m ? (video + (size_t)b*1024*E_DIM)
                         : (audio + (size_t)b*1024*E_DIM);
    int t = threadIdx.x;
    __shared__ float frow[E_DIM];
    __shared__ __align__(16) float kl[DK];
    __shared__ float red[4][DK];
    for (int i = t; i < E_DIM; i += 256) {
        float div = expf((float)(i & ~1) * KC);
        float arg = (float)mrow * div;
        float pe  = (i & 1) ? cosf(arg) : sinf(arg);
        frow[i] = src[i] + pe;
    }
    __syncthreads();
    int d = t & 63, es = t >> 6;
    const float* wkcol = Wk + (size_t)(h*DK) + d;
    float part = 0.f;
    #pragma unroll 8
    for (int e = es*128; e < es*128 + 128; ++e)
        part = fmaf(frow[e], wkcol[(size_t)e*HID], part);
    red[es][d] = part;
    __syncthreads();
    if (t < DK)
        kl[t] = bk[h*DK + t] + red[0][t] + red[1][t] + red[2][t] + red[3][t];
    __syncthreads();
    #pragma unroll
    for (int s = 0; s < 2; ++s) {
        int e = s*256 + t;
        const float4* wq4 = (const float4*)(Wq + (size_t)e*HID + h*DK);
        const float4* k4  = (const float4*)kl;
        float acc = 0.f;
        #pragma unroll
        for (int d4 = 0; d4 < 16; ++d4) {
            float4 w = wq4[d4]; float4 kk = k4[d4];
            acc = fmaf(w.x,kk.x, fmaf(w.y,kk.y, fmaf(w.z,kk.z, fmaf(w.w,kk.w, acc))));
        }
        uws[((size_t)bm*NH + h)*E_DIM + e] = acc * 0.125f;
    }
    if (t < 64) {
        float prod = (t < DK) ? bq[h*DK + t] * kl[t] : 0.f;
        float tot = wave_reduce_sum_dpp(prod);
        if (t == 0) cws[bm*NH + h] = tot * 0.125f;
    }
}

// K2: LDS-shared fused kernel. Block owns (b, chunk of CRW rows), computes all 20 p.
// Phase A: stage F(+pe) and u into LDS once (coalesced).
// Phase B: thread (r, p-pair) computes 2 full-E dots from LDS — no cross-lane reduce.
// Softmax: 20 threads, one p each, serial over CRW.
// Phase C: 4 waves x 5p, lanes split E; wgt broadcast from LDS.
// grid (nch, NB), block 256.
template<int CRW>
__global__ __launch_bounds__(256) void ba_fused_kernel(
        const float* __restrict__ audio, const float* __restrict__ video,
        const float* __restrict__ atok, const float* __restrict__ vtok,
        const float* __restrict__ btnk,
        const float* __restrict__ uws, const float* __restrict__ cws,
        float* __restrict__ wpart, float* __restrict__ mcs,
        float* __restrict__ lcs, int nch) {
    __shared__ __align__(16) float Fl[CRW*FPITCH];
    __shared__ __align__(16) float Ul[20*FPITCH];
    __shared__ float Sl[CRW*20];
    __shared__ float cadd_l[20];
    int b = blockIdx.y, chunk = blockIdx.x, t = threadIdx.x;
    int r0 = chunk*CRW;

    // ---- Phase A: stage F rows (+pe) and u into LDS ----
    for (int idx = t; idx < CRW*E_DIM; idx += 256) {
        int r = idx >> 9, e = idx & 511;
        int n = r0 + r;
        float val = 0.f;
        if (n < LTOT) {
            const float* src = row_src(b, n, audio, video, atok, vtok, btnk);
            float dv  = expf((float)(e & ~1) * KC);
            float arg = (float)n * dv;
            float pe  = (e & 1) ? cosf(arg) : sinf(arg);
            val = src[e] + pe;
        }
        Fl[r*FPITCH + e] = val;
    }
    for (int idx = t; idx < 20*E_DIM; idx += 256) {
        int p = idx >> 9, e = idx & 511;
        Ul[p*FPITCH + e] = uws[((size_t)(b*20 + p) << 9) + e];
    }
    if (t < 20) cadd_l[t] = cws[b*20 + t];
    __syncthreads();

    // ---- Phase B: dots. thread -> (r, p-pair). CRW*10 pairs. ----
    for (int pair = t; pair < CRW*10; pair += 256) {
        int r = pair / 10, pp = pair % 10;
        int p0 = pp*2, p1 = p0 + 1;
        const float4* Fr = (const float4*)(Fl + r*FPITCH);
        const float4* U0 = (const float4*)(Ul + p0*FPITCH);
        const float4* U1 = (const float4*)(Ul + p1*FPITCH);
        float4 a00 = make_float4(0,0,0,0), a01 = make_float4(0,0,0,0);
        float4 a10 = make_float4(0,0,0,0), a11 = make_float4(0,0,0,0);
        #pragma unroll 4
        for (int e4 = 0; e4 < 128; e4 += 2) {
            float4 f0 = Fr[e4], f1 = Fr[e4+1];
            fma4(a00, f0, U0[e4]);   fma4(a01, f1, U0[e4+1]);
            fma4(a10, f0, U1[e4]);   fma4(a11, f1, U1[e4+1]);
        }
        bool valid = (r0 + r < LTOT);
        float s0 = (a00.x+a00.y+a00.z+a00.w) + (a01.x+a01.y+a01.z+a01.w) + cadd_l[p0];
        float s1 = (a10.x+a10.y+a10.z+a10.w) + (a11.x+a11.y+a11.z+a11.w) + cadd_l[p1];
        Sl[r*20 + p0] = valid ? s0 : -1e30f;
        Sl[r*20 + p1] = valid ? s1 : -1e30f;
    }
    __syncthreads();

    // ---- chunk softmax stats; S -> weights in place ----
    if (t < 20) {
        float M = -1e30f;
        #pragma unroll
        for (int r = 0; r < CRW; ++r) M = fmaxf(M, Sl[r*20 + t]);
        float L = 0.f;
        #pragma unroll
        for (int r = 0; r < CRW; ++r) {
            float wv = __expf(Sl[r*20 + t] - M);
            Sl[r*20 + t] = wv;
            L += wv;
        }
        size_t ix = (size_t)(b*20 + t)*nch + chunk;
        mcs[ix] = M;
        lcs[ix] = L;
    }
    __syncthreads();

    // ---- Phase C: weighted feature sums. wave w -> p=5w..5w+4; lanes split E. ----
    int w = t >> 6, lane = t & 63;
    int eb = lane*8;
    float4 acc0[5], acc1[5];
    #pragma unroll
    for (int i = 0; i < 5; ++i) {
        acc0[i] = make_float4(0,0,0,0);
        acc1[i] = make_float4(0,0,0,0);
    }
    #pragma unroll 2
    for (int r = 0; r < CRW; ++r) {
        const float4* Fr = (const float4*)(Fl + r*FPITCH + eb);
        float4 f0 = Fr[0], f1 = Fr[1];
        #pragma unroll
        for (int i = 0; i < 5; ++i) {
            float wl = Sl[r*20 + w*5 + i];
            acc0[i].x = fmaf(wl, f0.x, acc0[i].x);
            acc0[i].y = fmaf(wl, f0.y, acc0[i].y);
            acc0[i].z = fmaf(wl, f0.z, acc0[i].z);
            acc0[i].w = fmaf(wl, f0.w, acc0[i].w);
            acc1[i].x = fmaf(wl, f1.x, acc1[i].x);
            acc1[i].y = fmaf(wl, f1.y, acc1[i].y);
            acc1[i].z = fmaf(wl, f1.z, acc1[i].z);
            acc1[i].w = fmaf(wl, f1.w, acc1[i].w);
        }
    }
    #pragma unroll
    for (int i = 0; i < 5; ++i) {
        float* dst = wpart + ((size_t)(b*20 + w*5 + i)*nch + chunk)*E_DIM + eb;
        *(float4*)dst       = acc0[i];
        *(float4*)(dst + 4) = acc1[i];
    }
}

// K3: reduce chunk partials with softmax rescale, project through Wv.
// grid (NH, 8), block 1024 = 16 waves.
__global__ __launch_bounds__(1024) void ba_outraw_kernel(
        const float* __restrict__ wpart, const float* __restrict__ mcs,
        const float* __restrict__ lcs,
        const float* __restrict__ Wv, const float* __restrict__ bv,
        float* __restrict__ orow, int nch) {
    int h = blockIdx.x, bm = blockIdx.y, t = threadIdx.x;
    int b = bm >> 1, m = bm & 1, p = m*10 + h;
    __shared__ float ml[128], ll[128], coefs[128];
    __shared__ float Msh, invLsh;
    __shared__ float wh[E_DIM];
    __shared__ float sh[2][E_DIM];
    __shared__ float red[16][64];
    const float* mrow = mcs + (size_t)(b*20 + p)*nch;
    const float* lrow = lcs + (size_t)(b*20 + p)*nch;
    if (t < nch) { ml[t] = mrow[t]; ll[t] = lrow[t]; }
    __syncthreads();
    if (t < 64) {
        float mv = -1e30f;
        for (int c = t; c < nch; c += 64) mv = fmaxf(mv, ml[c]);
        #pragma unroll
        for (int off = 1; off < 64; off <<= 1) mv = fmaxf(mv, __shfl_xor(mv, off, 64));
        if (t == 0) Msh = mv;
    }
    __syncthreads();
    float M = Msh;
    if (t < 64) {
        float lv = 0.f;
        for (int c = t; c < nch; c += 64) lv += ll[c] * __expf(ml[c] - M);
        lv = wave_reduce_sum_dpp(lv);
        if (t == 0) invLsh = 1.0f / lv;
    }
    __syncthreads();
    if (t < nch) coefs[t] = __expf(ml[t] - M) * invLsh;
    __syncthreads();
    int e = t & 511, half = t >> 9;
    const float* basep = wpart + (size_t)(b*20 + p)*nch*E_DIM;
    float acc = 0.f;
    int c0 = half ? (nch >> 1) : 0;
    int c1 = half ? nch : (nch >> 1);      // odd nch: upper half takes the extra chunk
    for (int c = c0; c < c1; ++c)
        acc = fmaf(basep[(size_t)c*E_DIM + e], coefs[c], acc);
    sh[half][e] = acc;
    __syncthreads();
    if (t < E_DIM) wh[t] = sh[0][t] + sh[1][t];
    __syncthreads();
    int d = t & 63, es = t >> 6;          // es 0..15, 32 e's each
    float part = 0.f;
    #pragma unroll 8
    for (int e2 = es*32; e2 < es*32 + 32; ++e2)
        part = fmaf(wh[e2], Wv[(size_t)e2*HID + h*DK + d], part);
    red[es][d] = part;
    __syncthreads();
    if (t < 64) {
        float s = 0.f;
        #pragma unroll
        for (int i = 0; i < 16; ++i) s += red[i][t];
        orow[(size_t)bm*HID + h*DK + t] = bv[h*DK + t] + s;
    }
}

// K4: fused layernorm + class predictions. grid (9, NB), block 512.
__global__ __launch_bounds__(512) void ba_lnpred_kernel(
        const float* __restrict__ orow,
        const float* __restrict__ g, const float* __restrict__ bb,
        const float* __restrict__ Wap, const float* __restrict__ bap,
        const float* __restrict__ Wvp, const float* __restrict__ bvp,
        float* __restrict__ out) {
    int b = blockIdx.y, t = threadIdx.x;
    const float* A = orow + (size_t)(2*b)*HID;
    const float* V = orow + (size_t)(2*b + 1)*HID;
    __shared__ float lnA[HID], lnV[HID];
    __shared__ float wred[4][8];
    __shared__ float psum[8][2][64];
    float sA = 0.f, qA = 0.f, sV = 0.f, qV = 0.f;
    for (int i = t; i < HID; i += 512) {
        float xa = A[i]; sA += xa; qA = fmaf(xa, xa, qA);
        float xv = V[i]; sV += xv; qV = fmaf(xv, xv, qV);
    }
    sA = wave_reduce_sum_dpp(sA); qA = wave_reduce_sum_dpp(qA);
    sV = wave_reduce_sum_dpp(sV); qV = wave_reduce_sum_dpp(qV);
    int w = t >> 6, lane = t & 63;
    if (lane == 0) { wred[0][w] = sA; wred[1][w] = qA; wred[2][w] = sV; wred[3][w] = qV; }
    __syncthreads();
    float tsA = 0.f, tqA = 0.f, tsV = 0.f, tqV = 0.f;
    #pragma unroll
    for (int i = 0; i < 8; ++i) {
        tsA += wred[0][i]; tqA += wred[1][i]; tsV += wred[2][i]; tqV += wred[3][i];
    }
    float meanA = tsA*(1.0f/HID), varA = tqA*(1.0f/HID) - meanA*meanA;
    float meanV = tsV*(1.0f/HID), varV = tqV*(1.0f/HID) - meanV*meanV;
    float rA = rsqrtf(varA + 1e-5f), rV = rsqrtf(varV + 1e-5f);
    for (int i = t; i < HID; i += 512) {
        float gg = g[i], bbv = bb[i];
        lnA[i] = (A[i] - meanA)*rA*gg + bbv;
        lnV[i] = (V[i] - meanV)*rV*gg + bbv;
    }
    __syncthreads();
    int c = blockIdx.x*64 + lane;
    int cc = (c < NCLS) ? c : (NCLS - 1);
    int j0 = w*80;
    float sa = 0.f, sv = 0.f;
    #pragma unroll 8
    for (int j = j0; j < j0 + 80; ++j) {
        sa = fmaf(lnA[j], Wap[(size_t)j*NCLS + cc], sa);
        sv = fmaf(lnV[j], Wvp[(size_t)j*NCLS + cc], sv);
    }
    psum[w][0][lane] = sa;
    psum[w][1][lane] = sv;
    __syncthreads();
    if (t < 64 && c < NCLS) {
        float ta = 0.f, tv = 0.f;
        #pragma unroll
        for (int i = 0; i < 8; ++i) { ta += psum[i][0][t]; tv += psum[i][1][t]; }
        out[(size_t)b*NCLS + c] = 0.5f*(ta + tv + bap[c] + bvp[c]);
    }
}

extern "C" void kernel_launch(void* const* d_in, const int* in_sizes, int n_in,
                              void* d_out, int out_size, void* d_ws, size_t ws_size,
                              hipStream_t stream) {
    const float* audio = (const float*)d_in[0];
    const float* video = (const float*)d_in[1];
    const float* atok  = (const float*)d_in[2];
    const float* vtok  = (const float*)d_in[3];
    const float* btnk  = (const float*)d_in[4];
    const float* Wk    = (const float*)d_in[5];
    const float* bk    = (const float*)d_in[6];
    const float* Wq    = (const float*)d_in[7];
    const float* bq    = (const float*)d_in[8];
    const float* Wv    = (const float*)d_in[9];
    const float* bv    = (const float*)d_in[10];
    const float* ln_g  = (const float*)d_in[11];
    const float* ln_b  = (const float*)d_in[12];
    const float* Wap   = (const float*)d_in[13];
    const float* bap   = (const float*)d_in[14];
    const float* Wvp   = (const float*)d_in[15];
    const float* bvp   = (const float*)d_in[16];
    float* out = (float*)d_out;
    float* ws  = (float*)d_ws;

    auto need = [](int nch) -> size_t {
        return (size_t)(8*NH*E_DIM) + 80
             + (size_t)NB*nch*20*E_DIM + 2*(size_t)NB*nch*20
             + 8*HID;
    };
    // CRW=17 -> nch=121; fallback CRW=51 -> nch=41 for small workspaces.
    int nch = (ws_size >= need(121)*sizeof(float)) ? 121 : 41;

    float* uws   = ws;
    float* cws   = uws + 8*NH*E_DIM;
    float* wpart = cws + 80;
    float* mcs   = wpart + (size_t)NB*nch*20*E_DIM;
    float* lcs   = mcs + (size_t)NB*nch*20;
    float* orw   = lcs + (size_t)NB*nch*20;

    ba_ku_kernel<<<dim3(NH, 8), 256, 0, stream>>>(audio, video, Wk, bk, Wq, bq, uws, cws);
    if (nch == 121)
        ba_fused_kernel<17><<<dim3(121, NB), 256, 0, stream>>>(
            audio, video, atok, vtok, btnk, uws, cws, wpart, mcs, lcs, 121);
    else
        ba_fused_kernel<51><<<dim3(41, NB), 256, 0, stream>>>(
            audio, video, atok, vtok, btnk, uws, cws, wpart, mcs, lcs, 41);
    ba_outraw_kernel<<<dim3(NH, 8), 1024, 0, stream>>>(wpart, mcs, lcs, Wv, bv, orw, nch);
    ba_lnpred_kernel<<<dim3(9, NB), 512, 0, stream>>>(orw, ln_g, ln_b,
                                                      Wap, bap, Wvp, bvp, out);
}

// Round 13
// 168.719 us; speedup vs baseline: 1.0474x; 1.0474x over previous
//
#include <hip/hip_runtime.h>
#include <cstddef>

#define E_DIM 512
#define HID   640
#define NH    10
#define DK    64
#define LTOT  2054
#define NCLS  527
#define NB    4
#define KC    (-0.0179889460390157f)   // -ln(10000)/512
#define SPITCH 2056                    // S row pitch (16B-aligned float4 stores)
#define NSLICE 64                      // wsum row-slices
#define CRS   32                       // rows per scores chunk (65*32=2080)
#define NSCH  65
#define CRWS  33                       // rows per wsum slice (64*33=2112)

// Wave64 sum-reduction via DPP (VALU pipe only).
__device__ __forceinline__ float wave_reduce_sum_dpp(float x) {
    float t;
    t = __int_as_float(__builtin_amdgcn_update_dpp(0, __float_as_int(x), 0x111, 0xf, 0xf, false)); x += t;
    t = __int_as_float(__builtin_amdgcn_update_dpp(0, __float_as_int(x), 0x112, 0xf, 0xf, false)); x += t;
    t = __int_as_float(__builtin_amdgcn_update_dpp(0, __float_as_int(x), 0x114, 0xf, 0xe, false)); x += t;
    t = __int_as_float(__builtin_amdgcn_update_dpp(0, __float_as_int(x), 0x118, 0xf, 0xc, false)); x += t;
    t = __int_as_float(__builtin_amdgcn_update_dpp(0, __float_as_int(x), 0x142, 0xa, 0xf, false)); x += t;
    t = __int_as_float(__builtin_amdgcn_update_dpp(0, __float_as_int(x), 0x143, 0xc, 0xf, false)); x += t;
    return __int_as_float(__builtin_amdgcn_readlane(__float_as_int(x), 63));
}

// Source row pointer for logical feats row n of batch b.
__device__ __forceinline__ const float* row_src(int b, int n,
        const float* au, const float* vi, const float* at,
        const float* vt, const float* bt) {
    if (n < 1024) return au + ((size_t)b*1024 + n)*E_DIM;
    if (n == 1024) return at;
    if (n < 1029) return bt + (size_t)(n-1025)*E_DIM;
    if (n < 2053) return vi + ((size_t)b*1024 + (n-1029))*E_DIM;
    return vt;
}

// K1: per-(h,bm) k-fragment + u-vector. grid (NH, 8), block 256.
// (bq term dropped: constant over n => softmax shift invariance)
__global__ __launch_bounds__(256) void ba_ku_kernel(
        const float* __restrict__ audio, const float* __restrict__ video,
        const float* __restrict__ Wk, const float* __restrict__ bk,
        const float* __restrict__ Wq,
        float* __restrict__ uws) {
    int h = blockIdx.x, bm = blockIdx.y;
    int b = bm >> 1, m = bm & 1;
    int mrow = m ? 1029 : 0;
    const float* src = m ? (video + (size_t)b*1024*E_DIM)
                         : (audio + (size_t)b*1024*E_DIM);
    int t = threadIdx.x;
    __shared__ float frow[E_DIM];
    __shared__ __align__(16) float kl[DK];
    __shared__ float red[4][DK];
    for (int i = t; i < E_DIM; i += 256) {
        float div = expf((float)(i & ~1) * KC);
        float arg = (float)mrow * div;
        float pe  = (i & 1) ? cosf(arg) : sinf(arg);
        frow[i] = src[i] + pe;
    }
    __syncthreads();
    int d = t & 63, es = t >> 6;
    const float* wkcol = Wk + (size_t)(h*DK) + d;
    float part = 0.f;
    #pragma unroll 8
    for (int e = es*128; e < es*128 + 128; ++e)
        part = fmaf(frow[e], wkcol[(size_t)e*HID], part);
    red[es][d] = part;
    __syncthreads();
    if (t < DK)
        kl[t] = bk[h*DK + t] + red[0][t] + red[1][t] + red[2][t] + red[3][t];
    __syncthreads();
    #pragma unroll
    for (int s = 0; s < 2; ++s) {
        int e = s*256 + t;
        const float4* wq4 = (const float4*)(Wq + (size_t)e*HID + h*DK);
        const float4* k4  = (const float4*)kl;
        float acc = 0.f;
        #pragma unroll
        for (int d4 = 0; d4 < 16; ++d4) {
            float4 w = wq4[d4]; float4 kk = k4[d4];
            acc = fmaf(w.x,kk.x, fmaf(w.y,kk.y, fmaf(w.z,kk.z, fmaf(w.w,kk.w, acc))));
        }
        uws[((size_t)bm*NH + h)*E_DIM + e] = acc * 0.125f;
    }
}

// K2: raw scores only. Rows fully independent — no softmax state.
// grid (NSCH, 5, NB), block 128 = 2 waves, wave owns p-pair; lanes split E.
// 4-row groups -> 8 interleaved DPP chains, one float4 store per p per group.
__global__ __launch_bounds__(128) void ba_scores_kernel(
        const float* __restrict__ audio, const float* __restrict__ video,
        const float* __restrict__ atok, const float* __restrict__ vtok,
        const float* __restrict__ btnk,
        const float* __restrict__ uws, float* __restrict__ S) {
    int b = blockIdx.z, chunk = blockIdx.x, t = threadIdx.x;
    int w = t >> 6, lane = t & 63;
    int pbase = (blockIdx.y*2 + w)*2;
    int eb = lane*8;
    int r0 = chunk*CRS;
    if (r0 >= LTOT) return;
    float4 u0[2], u1[2];
    #pragma unroll
    for (int i = 0; i < 2; ++i) {
        const float4* up = (const float4*)(uws + (size_t)(b*20 + pbase + i)*E_DIM + eb);
        u0[i] = up[0]; u1[i] = up[1];
    }
    float sn[4], cn[4], sd[4], cd[4];
    #pragma unroll
    for (int q = 0; q < 4; ++q) {
        float dv = expf((float)(eb + 2*q) * KC);
        sd[q] = sinf(dv); cd[q] = cosf(dv);
        float a = (float)r0 * dv;
        sn[q] = sinf(a); cn[q] = cosf(a);
    }
    int rend = min(r0 + CRS, LTOT);

#define ADV_ROT() { \
    _Pragma("unroll") \
    for (int q = 0; q < 4; ++q) { \
        float s2_ = fmaf(sn[q], cd[q],  cn[q]*sd[q]); \
        float c2_ = fmaf(cn[q], cd[q], -sn[q]*sd[q]); \
        sn[q] = s2_; cn[q] = c2_; } }

#define MAKE_FP(fp, x0, x1) { \
    (fp)[0]=(x0).x+sn[0]; (fp)[1]=(x0).y+cn[0]; (fp)[2]=(x0).z+sn[1]; (fp)[3]=(x0).w+cn[1]; \
    (fp)[4]=(x1).x+sn[2]; (fp)[5]=(x1).y+cn[2]; (fp)[6]=(x1).z+sn[3]; (fp)[7]=(x1).w+cn[3]; }

#define DOT8(res, fp, i) { \
    float a_; \
    a_ = (fp)[0]*u0[i].x; \
    a_ = fmaf((fp)[1], u0[i].y, a_); \
    a_ = fmaf((fp)[2], u0[i].z, a_); \
    a_ = fmaf((fp)[3], u0[i].w, a_); \
    a_ = fmaf((fp)[4], u1[i].x, a_); \
    a_ = fmaf((fp)[5], u1[i].y, a_); \
    a_ = fmaf((fp)[6], u1[i].z, a_); \
    a_ = fmaf((fp)[7], u1[i].w, a_); \
    (res) = a_; }

    float* S0 = S + (size_t)(b*20 + pbase)*SPITCH;
    float* S1 = S + (size_t)(b*20 + pbase + 1)*SPITCH;
    int r = r0;
    for (; r + 3 < rend; r += 4) {
        const float* s0p = row_src(b, r,   audio, video, atok, vtok, btnk);
        const float* s1p = row_src(b, r+1, audio, video, atok, vtok, btnk);
        const float* s2p = row_src(b, r+2, audio, video, atok, vtok, btnk);
        const float* s3p = row_src(b, r+3, audio, video, atok, vtok, btnk);
        float4 x00 = *(const float4*)(s0p + eb), x01 = *(const float4*)(s0p + eb + 4);
        float4 x10 = *(const float4*)(s1p + eb), x11 = *(const float4*)(s1p + eb + 4);
        float4 x20 = *(const float4*)(s2p + eb), x21 = *(const float4*)(s2p + eb + 4);
        float4 x30 = *(const float4*)(s3p + eb), x31 = *(const float4*)(s3p + eb + 4);
        float fp0[8], fp1[8], fp2[8], fp3[8];
        MAKE_FP(fp0, x00, x01); ADV_ROT();
        MAKE_FP(fp1, x10, x11); ADV_ROT();
        MAKE_FP(fp2, x20, x21); ADV_ROT();
        MAKE_FP(fp3, x30, x31); ADV_ROT();
        float d0, d1, d2, d3, d4, d5, d6, d7;
        DOT8(d0, fp0, 0); DOT8(d1, fp0, 1);
        DOT8(d2, fp1, 0); DOT8(d3, fp1, 1);
        DOT8(d4, fp2, 0); DOT8(d5, fp2, 1);
        DOT8(d6, fp3, 0); DOT8(d7, fp3, 1);
        float a0 = wave_reduce_sum_dpp(d0);
        float a1 = wave_reduce_sum_dpp(d1);
        float b0 = wave_reduce_sum_dpp(d2);
        float b1 = wave_reduce_sum_dpp(d3);
        float c0 = wave_reduce_sum_dpp(d4);
        float c1 = wave_reduce_sum_dpp(d5);
        float e0 = wave_reduce_sum_dpp(d6);
        float e1 = wave_reduce_sum_dpp(d7);
        float4 v = (lane == 0) ? make_float4(a0, b0, c0, e0)
                               : make_float4(a1, b1, c1, e1);
        if (lane < 2) {
            float* dst = (lane == 0) ? (S0 + r) : (S1 + r);
            *(float4*)dst = v;
        }
    }
    for (; r < rend; ++r) {
        const float* s0p = row_src(b, r, audio, video, atok, vtok, btnk);
        float4 x00 = *(const float4*)(s0p + eb), x01 = *(const float4*)(s0p + eb + 4);
        float fp0[8];
        MAKE_FP(fp0, x00, x01); ADV_ROT();
        float d0, d1;
        DOT8(d0, fp0, 0); DOT8(d1, fp0, 1);
        float a0 = wave_reduce_sum_dpp(d0);
        float a1 = wave_reduce_sum_dpp(d1);
        if (lane == 0) S0[r] = a0;
        if (lane == 1) S1[r] = a1;
    }
#undef ADV_ROT
#undef MAKE_FP
#undef DOT8
}

// K3: exact softmax stats per (b,p) row. grid 80, block 256.
__global__ void ba_stats_kernel(const float* __restrict__ S,
                                float* __restrict__ Mws, float* __restrict__ Iws) {
    int row = blockIdx.x, t = threadIdx.x;
    const float* Sr = S + (size_t)row*SPITCH;
    __shared__ float red[256];
    float lm = -1e30f;
    for (int i = t; i < LTOT; i += 256) lm = fmaxf(lm, Sr[i]);
    red[t] = lm; __syncthreads();
    for (int s = 128; s; s >>= 1) { if (t < s) red[t] = fmaxf(red[t], red[t+s]); __syncthreads(); }
    float M = red[0]; __syncthreads();
    float ls = 0.f;
    for (int i = t; i < LTOT; i += 256) ls += __expf(Sr[i] - M);
    red[t] = ls; __syncthreads();
    for (int s = 128; s; s >>= 1) { if (t < s) red[t] += red[t+s]; __syncthreads(); }
    if (t == 0) { Mws[row] = M; Iws[row] = 1.0f / red[0]; }
}

// K4: weighted feature sum with FINAL weights — pure streaming fma, no state.
// grid (NSLICE, NB), block 256 = 4 waves x 5 p; lanes split E.
// wpart layout: [(b*20+p)*NSLICE + slice][E_DIM], already normalized.
__global__ __launch_bounds__(256) void ba_wsum_kernel(
        const float* __restrict__ audio, const float* __restrict__ video,
        const float* __restrict__ atok, const float* __restrict__ vtok,
        const float* __restrict__ btnk,
        const float* __restrict__ S, const float* __restrict__ Mws,
        const float* __restrict__ Iws, float* __restrict__ wpart) {
    int b = blockIdx.y, sl = blockIdx.x, t = threadIdx.x;
    int w = t >> 6, lane = t & 63;
    int p0 = w*5, eb = lane*8;
    float M[5], I[5];
    #pragma unroll
    for (int i = 0; i < 5; ++i) {
        M[i] = Mws[b*20 + p0 + i];
        I[i] = Iws[b*20 + p0 + i];
    }
    int r0 = sl*CRWS;
    float sn[4], cn[4], sd[4], cd[4];
    #pragma unroll
    for (int q = 0; q < 4; ++q) {
        float dv = expf((float)(eb + 2*q) * KC);
        sd[q] = sinf(dv); cd[q] = cosf(dv);
        float a = (float)r0 * dv;
        sn[q] = sinf(a); cn[q] = cosf(a);
    }
    float acc[5][8];
    #pragma unroll
    for (int i = 0; i < 5; ++i)
        #pragma unroll
        for (int j = 0; j < 8; ++j) acc[i][j] = 0.f;
    int rend = min(r0 + CRWS, LTOT);
    for (int r = r0; r < rend; ++r) {
        const float* src = row_src(b, r, audio, video, atok, vtok, btnk);
        float4 f0 = *(const float4*)(src + eb);
        float4 f1 = *(const float4*)(src + eb + 4);
        float fp[8];
        fp[0]=f0.x+sn[0]; fp[1]=f0.y+cn[0]; fp[2]=f0.z+sn[1]; fp[3]=f0.w+cn[1];
        fp[4]=f1.x+sn[2]; fp[5]=f1.y+cn[2]; fp[6]=f1.z+sn[3]; fp[7]=f1.w+cn[3];
        #pragma unroll
        for (int q = 0; q < 4; ++q) {
            float s2 = fmaf(sn[q], cd[q],  cn[q]*sd[q]);
            float c2 = fmaf(cn[q], cd[q], -sn[q]*sd[q]);
            sn[q] = s2; cn[q] = c2;
        }
        #pragma unroll
        for (int i = 0; i < 5; ++i) {
            float wgt = __expf(S[(size_t)(b*20 + p0 + i)*SPITCH + r] - M[i]) * I[i];
            #pragma unroll
            for (int j = 0; j < 8; ++j) acc[i][j] = fmaf(wgt, fp[j], acc[i][j]);
        }
    }
    #pragma unroll
    for (int i = 0; i < 5; ++i) {
        float* dst = wpart + ((size_t)(b*20 + p0 + i)*NSLICE + sl)*E_DIM + eb;
        *(float4*)dst       = make_float4(acc[i][0], acc[i][1], acc[i][2], acc[i][3]);
        *(float4*)(dst + 4) = make_float4(acc[i][4], acc[i][5], acc[i][6], acc[i][7]);
    }
}

// K5: sum normalized slices, project through Wv. grid (NH, 8), block 1024.
__global__ __launch_bounds__(1024) void ba_outraw_kernel(
        const float* __restrict__ wpart,
        const float* __restrict__ Wv, const float* __restrict__ bv,
        float* __restrict__ orow) {
    int h = blockIdx.x, bm = blockIdx.y, t = threadIdx.x;
    int b = bm >> 1, m = bm & 1, p = m*10 + h;
    __shared__ float wh[E_DIM];
    __shared__ float sh[2][E_DIM];
    __shared__ float red[16][64];
    int e = t & 511, half = t >> 9;
    const float* basep = wpart + (size_t)(b*20 + p)*NSLICE*E_DIM;
    float acc = 0.f;
    int c0 = half*(NSLICE/2), c1 = c0 + (NSLICE/2);
    for (int c = c0; c < c1; ++c)
        acc += basep[(size_t)c*E_DIM + e];
    sh[half][e] = acc;
    __syncthreads();
    if (t < E_DIM) wh[t] = sh[0][t] + sh[1][t];
    __syncthreads();
    int d = t & 63, es = t >> 6;          // es 0..15, 32 e's each
    float part = 0.f;
    #pragma unroll 8
    for (int e2 = es*32; e2 < es*32 + 32; ++e2)
        part = fmaf(wh[e2], Wv[(size_t)e2*HID + h*DK + d], part);
    red[es][d] = part;
    __syncthreads();
    if (t < 64) {
        float s = 0.f;
        #pragma unroll
        for (int i = 0; i < 16; ++i) s += red[i][t];
        orow[(size_t)bm*HID + h*DK + t] = bv[h*DK + t] + s;
    }
}

// K6: fused layernorm + class predictions. grid (9, NB), block 512.
__global__ __launch_bounds__(512) void ba_lnpred_kernel(
        const float* __restrict__ orow,
        const float* __restrict__ g, const float* __restrict__ bb,
        const float* __restrict__ Wap, const float* __restrict__ bap,
        const float* __restrict__ Wvp, const float* __restrict__ bvp,
        float* __restrict__ out) {
    int b = blockIdx.y, t = threadIdx.x;
    const float* A = orow + (size_t)(2*b)*HID;
    const float* V = orow + (size_t)(2*b + 1)*HID;
    __shared__ float lnA[HID], lnV[HID];
    __shared__ float wred[4][8];
    __shared__ float psum[8][2][64];
    float sA = 0.f, qA = 0.f, sV = 0.f, qV = 0.f;
    for (int i = t; i < HID; i += 512) {
        float xa = A[i]; sA += xa; qA = fmaf(xa, xa, qA);
        float xv = V[i]; sV += xv; qV = fmaf(xv, xv, qV);
    }
    sA = wave_reduce_sum_dpp(sA); qA = wave_reduce_sum_dpp(qA);
    sV = wave_reduce_sum_dpp(sV); qV = wave_reduce_sum_dpp(qV);
    int w = t >> 6, lane = t & 63;
    if (lane == 0) { wred[0][w] = sA; wred[1][w] = qA; wred[2][w] = sV; wred[3][w] = qV; }
    __syncthreads();
    float tsA = 0.f, tqA = 0.f, tsV = 0.f, tqV = 0.f;
    #pragma unroll
    for (int i = 0; i < 8; ++i) {
        tsA += wred[0][i]; tqA += wred[1][i]; tsV += wred[2][i]; tqV += wred[3][i];
    }
    float meanA = tsA*(1.0f/HID), varA = tqA*(1.0f/HID) - meanA*meanA;
    float meanV = tsV*(1.0f/HID), varV = tqV*(1.0f/HID) - meanV*meanV;
    float rA = rsqrtf(varA + 1e-5f), rV = rsqrtf(varV + 1e-5f);
    for (int i = t; i < HID; i += 512) {
        float gg = g[i], bbv = bb[i];
        lnA[i] = (A[i] - meanA)*rA*gg + bbv;
        lnV[i] = (V[i] - meanV)*rV*gg + bbv;
    }
    __syncthreads();
    int c = blockIdx.x*64 + lane;
    int cc = (c < NCLS) ? c : (NCLS - 1);
    int j0 = w*80;
    float sa = 0.f, sv = 0.f;
    #pragma unroll 8
    for (int j = j0; j < j0 + 80; ++j) {
        sa = fmaf(lnA[j], Wap[(size_t)j*NCLS + cc], sa);
        sv = fmaf(lnV[j], Wvp[(size_t)j*NCLS + cc], sv);
    }
    psum[w][0][lane] = sa;
    psum[w][1][lane] = sv;
    __syncthreads();
    if (t < 64 && c < NCLS) {
        float ta = 0.f, tv = 0.f;
        #pragma unroll
        for (int i = 0; i < 8; ++i) { ta += psum[i][0][t]; tv += psum[i][1][t]; }
        out[(size_t)b*NCLS + c] = 0.5f*(ta + tv + bap[c] + bvp[c]);
    }
}

extern "C" void kernel_launch(void* const* d_in, const int* in_sizes, int n_in,
                              void* d_out, int out_size, void* d_ws, size_t ws_size,
                              hipStream_t stream) {
    const float* audio = (const float*)d_in[0];
    const float* video = (const float*)d_in[1];
    const float* atok  = (const float*)d_in[2];
    const float* vtok  = (const float*)d_in[3];
    const float* btnk  = (const float*)d_in[4];
    const float* Wk    = (const float*)d_in[5];
    const float* bk    = (const float*)d_in[6];
    const float* Wq    = (const float*)d_in[7];
    const float* Wv    = (const float*)d_in[9];
    const float* bv    = (const float*)d_in[10];
    const float* ln_g  = (const float*)d_in[11];
    const float* ln_b  = (const float*)d_in[12];
    const float* Wap   = (const float*)d_in[13];
    const float* bap   = (const float*)d_in[14];
    const float* Wvp   = (const float*)d_in[15];
    const float* bvp   = (const float*)d_in[16];
    float* out = (float*)d_out;
    float* ws  = (float*)d_ws;

    float* uws   = ws;                                   // 8*NH*E_DIM = 40960
    float* S     = uws + 8*NH*E_DIM;                     // 80*SPITCH = 164480
    float* Mws   = S + (size_t)80*SPITCH;                // 80
    float* Iws   = Mws + 80;                             // 80
    float* wpart = Iws + 80;                             // 80*NSLICE*E_DIM = 2,621,440
    float* orw   = wpart + (size_t)80*NSLICE*E_DIM;      // 8*HID

    ba_ku_kernel<<<dim3(NH, 8), 256, 0, stream>>>(audio, video, Wk, bk, Wq, uws);
    ba_scores_kernel<<<dim3(NSCH, 5, NB), 128, 0, stream>>>(audio, video, atok, vtok,
                                                            btnk, uws, S);
    ba_stats_kernel<<<80, 256, 0, stream>>>(S, Mws, Iws);
    ba_wsum_kernel<<<dim3(NSLICE, NB), 256, 0, stream>>>(audio, video, atok, vtok, btnk,
                                                         S, Mws, Iws, wpart);
    ba_outraw_kernel<<<dim3(NH, 8), 1024, 0, stream>>>(wpart, Wv, bv, orw);
    ba_lnpred_kernel<<<dim3(9, NB), 512, 0, stream>>>(orw, ln_g, ln_b,
                                                      Wap, bap, Wvp, bvp, out);
}

// Round 14
// 160.990 us; speedup vs baseline: 1.0977x; 1.0480x over previous
//
#include <hip/hip_runtime.h>
#include <cstddef>

#define E_DIM 512
#define HID   640
#define NH    10
#define DK    64
#define LTOT  2054
#define NCLS  527
#define NB    4
#define KC    (-0.0179889460390157f)   // -ln(10000)/512

// Wave64 sum-reduction via DPP (VALU pipe only, no LDS/DS ops).
__device__ __forceinline__ float wave_reduce_sum_dpp(float x) {
    float t;
    t = __int_as_float(__builtin_amdgcn_update_dpp(0, __float_as_int(x), 0x111, 0xf, 0xf, false)); x += t;
    t = __int_as_float(__builtin_amdgcn_update_dpp(0, __float_as_int(x), 0x112, 0xf, 0xf, false)); x += t;
    t = __int_as_float(__builtin_amdgcn_update_dpp(0, __float_as_int(x), 0x114, 0xf, 0xe, false)); x += t;
    t = __int_as_float(__builtin_amdgcn_update_dpp(0, __float_as_int(x), 0x118, 0xf, 0xc, false)); x += t;
    t = __int_as_float(__builtin_amdgcn_update_dpp(0, __float_as_int(x), 0x142, 0xa, 0xf, false)); x += t;
    t = __int_as_float(__builtin_amdgcn_update_dpp(0, __float_as_int(x), 0x143, 0xc, 0xf, false)); x += t;
    return __int_as_float(__builtin_amdgcn_readlane(__float_as_int(x), 63));
}

// Source row pointer for logical feats row n of batch b.
__device__ __forceinline__ const float* row_src(int b, int n,
        const float* au, const float* vi, const float* at,
        const float* vt, const float* bt) {
    if (n < 1024) return au + ((size_t)b*1024 + n)*E_DIM;
    if (n == 1024) return at;
    if (n < 1029) return bt + (size_t)(n-1025)*E_DIM;
    if (n < 2053) return vi + ((size_t)b*1024 + (n-1029))*E_DIM;
    return vt;
}

// K1: per-(h,bm) k-fragment + u-vector. grid (NH, 8), block 256.
// (bq·k constant dropped: softmax shift invariance)
__global__ __launch_bounds__(256) void ba_ku_kernel(
        const float* __restrict__ audio, const float* __restrict__ video,
        const float* __restrict__ Wk, const float* __restrict__ bk,
        const float* __restrict__ Wq,
        float* __restrict__ uws) {
    int h = blockIdx.x, bm = blockIdx.y;
    int b = bm >> 1, m = bm & 1;
    int mrow = m ? 1029 : 0;
    const float* src = m ? (video + (size_t)b*1024*E_DIM)
                         : (audio + (size_t)b*1024*E_DIM);
    int t = threadIdx.x;
    __shared__ float frow[E_DIM];
    __shared__ __align__(16) float kl[DK];
    __shared__ float red[4][DK];
    for (int i = t; i < E_DIM; i += 256) {
        float div = expf((float)(i & ~1) * KC);
        float arg = (float)mrow * div;
        float pe  = (i & 1) ? cosf(arg) : sinf(arg);
        frow[i] = src[i] + pe;
    }
    __syncthreads();
    int d = t & 63, es = t >> 6;
    const float* wkcol = Wk + (size_t)(h*DK) + d;
    float part = 0.f;
    #pragma unroll 8
    for (int e = es*128; e < es*128 + 128; ++e)
        part = fmaf(frow[e], wkcol[(size_t)e*HID], part);
    red[es][d] = part;
    __syncthreads();
    if (t < DK)
        kl[t] = bk[h*DK + t] + red[0][t] + red[1][t] + red[2][t] + red[3][t];
    __syncthreads();
    #pragma unroll
    for (int s = 0; s < 2; ++s) {
        int e = s*256 + t;
        const float4* wq4 = (const float4*)(Wq + (size_t)e*HID + h*DK);
        const float4* k4  = (const float4*)kl;
        float acc = 0.f;
        #pragma unroll
        for (int d4 = 0; d4 < 16; ++d4) {
            float4 w = wq4[d4]; float4 kk = k4[d4];
            acc = fmaf(w.x,kk.x, fmaf(w.y,kk.y, fmaf(w.z,kk.z, fmaf(w.w,kk.w, acc))));
        }
        uws[((size_t)bm*NH + h)*E_DIM + e] = acc * 0.125f;
    }
}

// K2: fused scores + online softmax + weighted feature sum.
// grid (nch, 5, NB), block 128 = 2 waves, wave owns one p-pair; lanes split E.
// Rows processed in groups of 4: 8 independent reduce chains interleave.
__global__ __launch_bounds__(128) void ba_fused_kernel(
        const float* __restrict__ audio, const float* __restrict__ video,
        const float* __restrict__ atok, const float* __restrict__ vtok,
        const float* __restrict__ btnk,
        const float* __restrict__ uws,
        float* __restrict__ wpart, float* __restrict__ mcs,
        float* __restrict__ lcs, int nch, int crw) {
    int b = blockIdx.z, chunk = blockIdx.x, t = threadIdx.x;
    int w = t >> 6, lane = t & 63;
    int pbase = (blockIdx.y*2 + w)*2;
    int eb = lane*8;
    float4 u0[2], u1[2];
    #pragma unroll
    for (int i = 0; i < 2; ++i) {
        const float4* up = (const float4*)(uws + (size_t)(b*20 + pbase + i)*E_DIM + eb);
        u0[i] = up[0]; u1[i] = up[1];
    }
    int r0 = chunk*crw;
    float sn[4], cn[4], sd[4], cd[4];
    #pragma unroll
    for (int q = 0; q < 4; ++q) {
        float dv = expf((float)(eb + 2*q) * KC);
        sd[q] = sinf(dv); cd[q] = cosf(dv);
        float a = (float)r0 * dv;
        sn[q] = sinf(a); cn[q] = cosf(a);
    }
    float m[2], l[2], acc[2][8];
    #pragma unroll
    for (int i = 0; i < 2; ++i) {
        m[i] = -1e30f; l[i] = 0.f;
        #pragma unroll
        for (int j = 0; j < 8; ++j) acc[i][j] = 0.f;
    }
    int rend = min(r0 + crw, LTOT);

#define ADV_ROT() { \
    _Pragma("unroll") \
    for (int q = 0; q < 4; ++q) { \
        float s2_ = fmaf(sn[q], cd[q],  cn[q]*sd[q]); \
        float c2_ = fmaf(cn[q], cd[q], -sn[q]*sd[q]); \
        sn[q] = s2_; cn[q] = c2_; } }

#define MAKE_FP(fp, x0, x1) { \
    (fp)[0]=(x0).x+sn[0]; (fp)[1]=(x0).y+cn[0]; (fp)[2]=(x0).z+sn[1]; (fp)[3]=(x0).w+cn[1]; \
    (fp)[4]=(x1).x+sn[2]; (fp)[5]=(x1).y+cn[2]; (fp)[6]=(x1).z+sn[3]; (fp)[7]=(x1).w+cn[3]; }

#define DOT8(res, fp, i) { \
    float a_; \
    a_ = (fp)[0]*u0[i].x; \
    a_ = fmaf((fp)[1], u0[i].y, a_); \
    a_ = fmaf((fp)[2], u0[i].z, a_); \
    a_ = fmaf((fp)[3], u0[i].w, a_); \
    a_ = fmaf((fp)[4], u1[i].x, a_); \
    a_ = fmaf((fp)[5], u1[i].y, a_); \
    a_ = fmaf((fp)[6], u1[i].z, a_); \
    a_ = fmaf((fp)[7], u1[i].w, a_); \
    (res) = a_; }

#define SOFT_UPD(i, sc, fp) { \
    if ((sc) > m[i]) { \
        float scale_ = __expf(m[i] - (sc)); \
        m[i] = (sc); \
        l[i] = fmaf(l[i], scale_, 1.f); \
        _Pragma("unroll") \
        for (int j = 0; j < 8; ++j) acc[i][j] = fmaf(acc[i][j], scale_, (fp)[j]); \
    } else { \
        float wg_ = __expf((sc) - m[i]); \
        l[i] += wg_; \
        _Pragma("unroll") \
        for (int j = 0; j < 8; ++j) acc[i][j] = fmaf(wg_, (fp)[j], acc[i][j]); } }

    int r = r0;
    for (; r + 3 < rend; r += 4) {
        const float* s0p = row_src(b, r,   audio, video, atok, vtok, btnk);
        const float* s1p = row_src(b, r+1, audio, video, atok, vtok, btnk);
        const float* s2p = row_src(b, r+2, audio, video, atok, vtok, btnk);
        const float* s3p = row_src(b, r+3, audio, video, atok, vtok, btnk);
        float4 x00 = *(const float4*)(s0p + eb), x01 = *(const float4*)(s0p + eb + 4);
        float4 x10 = *(const float4*)(s1p + eb), x11 = *(const float4*)(s1p + eb + 4);
        float4 x20 = *(const float4*)(s2p + eb), x21 = *(const float4*)(s2p + eb + 4);
        float4 x30 = *(const float4*)(s3p + eb), x31 = *(const float4*)(s3p + eb + 4);
        float fp0[8], fp1[8], fp2[8], fp3[8];
        MAKE_FP(fp0, x00, x01); ADV_ROT();
        MAKE_FP(fp1, x10, x11); ADV_ROT();
        MAKE_FP(fp2, x20, x21); ADV_ROT();
        MAKE_FP(fp3, x30, x31); ADV_ROT();
        float d0, d1, d2, d3, d4, d5, d6, d7;
        DOT8(d0, fp0, 0); DOT8(d1, fp0, 1);
        DOT8(d2, fp1, 0); DOT8(d3, fp1, 1);
        DOT8(d4, fp2, 0); DOT8(d5, fp2, 1);
        DOT8(d6, fp3, 0); DOT8(d7, fp3, 1);
        float sc0 = wave_reduce_sum_dpp(d0);
        float sc1 = wave_reduce_sum_dpp(d1);
        float sc2 = wave_reduce_sum_dpp(d2);
        float sc3 = wave_reduce_sum_dpp(d3);
        float sc4 = wave_reduce_sum_dpp(d4);
        float sc5 = wave_reduce_sum_dpp(d5);
        float sc6 = wave_reduce_sum_dpp(d6);
        float sc7 = wave_reduce_sum_dpp(d7);
        SOFT_UPD(0, sc0, fp0); SOFT_UPD(0, sc2, fp1);
        SOFT_UPD(0, sc4, fp2); SOFT_UPD(0, sc6, fp3);
        SOFT_UPD(1, sc1, fp0); SOFT_UPD(1, sc3, fp1);
        SOFT_UPD(1, sc5, fp2); SOFT_UPD(1, sc7, fp3);
    }
    for (; r < rend; ++r) {
        const float* s0p = row_src(b, r, audio, video, atok, vtok, btnk);
        float4 x00 = *(const float4*)(s0p + eb), x01 = *(const float4*)(s0p + eb + 4);
        float fp0[8];
        MAKE_FP(fp0, x00, x01); ADV_ROT();
        float d0, d1;
        DOT8(d0, fp0, 0); DOT8(d1, fp0, 1);
        float sc0 = wave_reduce_sum_dpp(d0);
        float sc1 = wave_reduce_sum_dpp(d1);
        SOFT_UPD(0, sc0, fp0);
        SOFT_UPD(1, sc1, fp0);
    }
    #pragma unroll
    for (int i = 0; i < 2; ++i) {
        float* dst = wpart + ((size_t)(b*20 + pbase + i)*nch + chunk)*E_DIM + eb;
        *(float4*)dst       = make_float4(acc[i][0], acc[i][1], acc[i][2], acc[i][3]);
        *(float4*)(dst + 4) = make_float4(acc[i][4], acc[i][5], acc[i][6], acc[i][7]);
    }
    float mv = (lane == 0) ? m[0] : m[1];
    float lv = (lane == 0) ? l[0] : l[1];
    if (lane < 2) {
        size_t ix = (size_t)(b*20 + pbase + lane)*nch + chunk;
        mcs[ix] = mv;
        lcs[ix] = lv;
    }
#undef ADV_ROT
#undef MAKE_FP
#undef DOT8
#undef SOFT_UPD
}

// K3: reduce chunk partials with softmax rescale, project through Wv.
// grid (NH, 8), block 1024 = 16 waves. Parallel M/L reduction, streaming wpart.
__global__ __launch_bounds__(1024) void ba_outraw_kernel(
        const float* __restrict__ wpart, const float* __restrict__ mcs,
        const float* __restrict__ lcs,
        const float* __restrict__ Wv, const float* __restrict__ bv,
        float* __restrict__ orow, int nch) {
    int h = blockIdx.x, bm = blockIdx.y, t = threadIdx.x;
    int b = bm >> 1, m = bm & 1, p = m*10 + h;
    __shared__ float ml[128], ll[128], coefs[128];
    __shared__ float Msh, invLsh;
    __shared__ float wh[E_DIM];
    __shared__ float sh[2][E_DIM];
    __shared__ float red[16][64];
    const float* mrow = mcs + (size_t)(b*20 + p)*nch;
    const float* lrow = lcs + (size_t)(b*20 + p)*nch;
    if (t < nch) { ml[t] = mrow[t]; ll[t] = lrow[t]; }
    __syncthreads();
    if (t < 64) {
        float mv = -1e30f;
        for (int c = t; c < nch; c += 64) mv = fmaxf(mv, ml[c]);
        #pragma unroll
        for (int off = 1; off < 64; off <<= 1) mv = fmaxf(mv, __shfl_xor(mv, off, 64));
        if (t == 0) Msh = mv;
    }
    __syncthreads();
    float M = Msh;
    if (t < 64) {
        float lv = 0.f;
        for (int c = t; c < nch; c += 64) lv += ll[c] * __expf(ml[c] - M);
        lv = wave_reduce_sum_dpp(lv);
        if (t == 0) invLsh = 1.0f / lv;
    }
    __syncthreads();
    if (t < nch) coefs[t] = __expf(ml[t] - M) * invLsh;
    __syncthreads();
    int e = t & 511, half = t >> 9;
    const float* basep = wpart + (size_t)(b*20 + p)*nch*E_DIM;
    float acc = 0.f;
    int c0 = half ? (nch >> 1) : 0;
    int c1 = half ? nch : (nch >> 1);
    for (int c = c0; c < c1; ++c)
        acc = fmaf(basep[(size_t)c*E_DIM + e], coefs[c], acc);
    sh[half][e] = acc;
    __syncthreads();
    if (t < E_DIM) wh[t] = sh[0][t] + sh[1][t];
    __syncthreads();
    int d = t & 63, es = t >> 6;          // es 0..15, 32 e's each
    float part = 0.f;
    #pragma unroll 8
    for (int e2 = es*32; e2 < es*32 + 32; ++e2)
        part = fmaf(wh[e2], Wv[(size_t)e2*HID + h*DK + d], part);
    red[es][d] = part;
    __syncthreads();
    if (t < 64) {
        float s = 0.f;
        #pragma unroll
        for (int i = 0; i < 16; ++i) s += red[i][t];
        orow[(size_t)bm*HID + h*DK + t] = bv[h*DK + t] + s;
    }
}

// K4: fused layernorm + class predictions. grid (9, NB), block 512.
__global__ __launch_bounds__(512) void ba_lnpred_kernel(
        const float* __restrict__ orow,
        const float* __restrict__ g, const float* __restrict__ bb,
        const float* __restrict__ Wap, const float* __restrict__ bap,
        const float* __restrict__ Wvp, const float* __restrict__ bvp,
        float* __restrict__ out) {
    int b = blockIdx.y, t = threadIdx.x;
    const float* A = orow + (size_t)(2*b)*HID;
    const float* V = orow + (size_t)(2*b + 1)*HID;
    __shared__ float lnA[HID], lnV[HID];
    __shared__ float wred[4][8];
    __shared__ float psum[8][2][64];
    float sA = 0.f, qA = 0.f, sV = 0.f, qV = 0.f;
    for (int i = t; i < HID; i += 512) {
        float xa = A[i]; sA += xa; qA = fmaf(xa, xa, qA);
        float xv = V[i]; sV += xv; qV = fmaf(xv, xv, qV);
    }
    sA = wave_reduce_sum_dpp(sA); qA = wave_reduce_sum_dpp(qA);
    sV = wave_reduce_sum_dpp(sV); qV = wave_reduce_sum_dpp(qV);
    int w = t >> 6, lane = t & 63;
    if (lane == 0) { wred[0][w] = sA; wred[1][w] = qA; wred[2][w] = sV; wred[3][w] = qV; }
    __syncthreads();
    float tsA = 0.f, tqA = 0.f, tsV = 0.f, tqV = 0.f;
    #pragma unroll
    for (int i = 0; i < 8; ++i) {
        tsA += wred[0][i]; tqA += wred[1][i]; tsV += wred[2][i]; tqV += wred[3][i];
    }
    float meanA = tsA*(1.0f/HID), varA = tqA*(1.0f/HID) - meanA*meanA;
    float meanV = tsV*(1.0f/HID), varV = tqV*(1.0f/HID) - meanV*meanV;
    float rA = rsqrtf(varA + 1e-5f), rV = rsqrtf(varV + 1e-5f);
    for (int i = t; i < HID; i += 512) {
        float gg = g[i], bbv = bb[i];
        lnA[i] = (A[i] - meanA)*rA*gg + bbv;
        lnV[i] = (V[i] - meanV)*rV*gg + bbv;
    }
    __syncthreads();
    int c = blockIdx.x*64 + lane;
    int cc = (c < NCLS) ? c : (NCLS - 1);
    int j0 = w*80;
    float sa = 0.f, sv = 0.f;
    #pragma unroll 8
    for (int j = j0; j < j0 + 80; ++j) {
        sa = fmaf(lnA[j], Wap[(size_t)j*NCLS + cc], sa);
        sv = fmaf(lnV[j], Wvp[(size_t)j*NCLS + cc], sv);
    }
    psum[w][0][lane] = sa;
    psum[w][1][lane] = sv;
    __syncthreads();
    if (t < 64 && c < NCLS) {
        float ta = 0.f, tv = 0.f;
        #pragma unroll
        for (int i = 0; i < 8; ++i) { ta += psum[i][0][t]; tv += psum[i][1][t]; }
        out[(size_t)b*NCLS + c] = 0.5f*(ta + tv + bap[c] + bvp[c]);
    }
}

extern "C" void kernel_launch(void* const* d_in, const int* in_sizes, int n_in,
                              void* d_out, int out_size, void* d_ws, size_t ws_size,
                              hipStream_t stream) {
    const float* audio = (const float*)d_in[0];
    const float* video = (const float*)d_in[1];
    const float* atok  = (const float*)d_in[2];
    const float* vtok  = (const float*)d_in[3];
    const float* btnk  = (const float*)d_in[4];
    const float* Wk    = (const float*)d_in[5];
    const float* bk    = (const float*)d_in[6];
    const float* Wq    = (const float*)d_in[7];
    const float* Wv    = (const float*)d_in[9];
    const float* bv    = (const float*)d_in[10];
    const float* ln_g  = (const float*)d_in[11];
    const float* ln_b  = (const float*)d_in[12];
    const float* Wap   = (const float*)d_in[13];
    const float* bap   = (const float*)d_in[14];
    const float* Wvp   = (const float*)d_in[15];
    const float* bvp   = (const float*)d_in[16];
    float* out = (float*)d_out;
    float* ws  = (float*)d_ws;

    auto need = [](int nch) -> size_t {
        return (size_t)(8*NH*E_DIM)
             + (size_t)NB*nch*20*E_DIM + 2*(size_t)NB*nch*20
             + 8*HID;
    };
    int nch = 40;
    if (ws_size >= need(128)*sizeof(float)) nch = 128;
    else if (ws_size >= need(64)*sizeof(float)) nch = 64;
    int crw = (LTOT + nch - 1) / nch;

    float* uws   = ws;
    float* wpart = uws + 8*NH*E_DIM;
    float* mcs   = wpart + (size_t)NB*nch*20*E_DIM;
    float* lcs   = mcs + (size_t)NB*nch*20;
    float* orw   = lcs + (size_t)NB*nch*20;

    ba_ku_kernel<<<dim3(NH, 8), 256, 0, stream>>>(audio, video, Wk, bk, Wq, uws);
    ba_fused_kernel<<<dim3(nch, 5, NB), 128, 0, stream>>>(audio, video, atok, vtok, btnk,
                                                          uws, wpart, mcs, lcs, nch, crw);
    ba_outraw_kernel<<<dim3(NH, 8), 1024, 0, stream>>>(wpart, mcs, lcs, Wv, bv, orw, nch);
    ba_lnpred_kernel<<<dim3(9, NB), 512, 0, stream>>>(orw, ln_g, ln_b,
                                                      Wap, bap, Wvp, bvp, out);
}